// Round 13
// baseline (526.520 us; speedup 1.0000x reference)
//
#include <hip/hip_runtime.h>
#include <hip/hip_bf16.h>

#define D 128
#define SLOTS 64
#define CSTR 72     // colidx row stride (u16); slots [deg,CSTR) hold dummy index N
#define BCAP 9216   // bucket capacity: mean 8192, +11 sigma

typedef short short8 __attribute__((ext_vector_type(8)));
typedef float f32x4 __attribute__((ext_vector_type(4)));
typedef unsigned short u16;
typedef unsigned int u32;

static __device__ __forceinline__ u16 f2bf(float f) {
  union { float f; unsigned u; } v; v.f = f;
  unsigned r = v.u + 0x7FFF + ((v.u >> 16) & 1);  // round-to-nearest-even
  return (u16)(r >> 16);
}
static __device__ __forceinline__ float bf2f(u16 h) {
  union { unsigned u; float f; } v; v.u = ((unsigned)h) << 16;
  return v.f;
}

// ---------- merged prep: binA | convertW | convertX(panel-major) | zero-rows ----------
__global__ __launch_bounds__(1024) void prep_kernel(
    const int* __restrict__ src, const int* __restrict__ dst,
    const float* __restrict__ x, const float* __restrict__ W1,
    const float* __restrict__ W2, int* __restrict__ gcount,
    u32* __restrict__ bedge, u16* __restrict__ W1th, u16* __restrict__ W1tl,
    u16* __restrict__ W2th, u16* __restrict__ W2tl, u32* __restrict__ xp,
    u32* __restrict__ hp, int E, int nbk, int wtotal, int nPairs,
    int nA, int nB, int nC, int N, int rowsP) {
  __shared__ int cnt[128];
  __shared__ int base[128];
  int b = blockIdx.x, t = threadIdx.x;
  if (b < nA) {
    // binA: LDS-binned edge scatter into 512-node dst-buckets
    if (t < nbk) cnt[t] = 0;
    __syncthreads();
    int e = b * 1024 + t;
    int bk = 0, p = 0;
    u32 payload = 0;
    bool valid = e < E;
    if (valid) {
      int d = dst[e];
      bk = d >> 9;
      payload = ((u32)src[e] << 9) | (u32)(d & 511);
      p = atomicAdd(&cnt[bk], 1);      // LDS atomic
    }
    __syncthreads();
    if (t < nbk) base[t] = cnt[t] ? atomicAdd(&gcount[t], cnt[t]) : 0;
    __syncthreads();
    if (valid) {
      int pos = base[bk] + p;
      if (pos < BCAP) bedge[(size_t)bk * BCAP + pos] = payload;
    }
  } else if (b < nA + nB) {
    // convert weights: hi/lo split bf16 in MFMA-fragment-tiled order
    // ((kt*8+nt)*64+lane)*8+j  <-  W[k][n], k=kt*32+(lane>>4)*8+j, n=nt*16+(lane&15)
    int idx = (b - nA) * 1024 + t;
    if (idx < wtotal) {
      int l = idx >> 14;
      int r = idx & 16383;
      int j = r & 7;
      int lane = (r >> 3) & 63;
      int tt = r >> 9;
      int kt = tt >> 3, nt = tt & 7;
      int k = kt * 32 + (lane >> 4) * 8 + j;
      int n = nt * 16 + (lane & 15);
      size_t s = (size_t)l * D * D + (size_t)k * D + n;
      float w1 = W1[s], w2 = W2[s];
      u16 h1 = f2bf(w1), h2 = f2bf(w2);
      W1th[idx] = h1; W1tl[idx] = f2bf(w1 - bf2f(h1));
      W2th[idx] = h2; W2tl[idx] = f2bf(w2 - bf2f(h2));
    }
  } else if (b < nA + nB + nC) {
    // convert x -> bf16 packed pairs, panel-major: panel p = 32 cols = 16 u32
    int i = (b - nA - nB) * 1024 + t;
    if (i < nPairs) {
      int node = i >> 6, pr = i & 63;
      float2 v = ((const float2*)x)[i];
      u32 pk = ((u32)f2bf(v.y) << 16) | f2bf(v.x);
      xp[((size_t)(pr >> 4) * rowsP + node) * 16 + (pr & 15)] = pk;
    }
  } else {
    // zero dummy row N of all panels of xp and hp
    if (t < 64) {
      xp[((size_t)(t >> 4) * rowsP + N) * 16 + (t & 15)] = 0;
      hp[((size_t)(t >> 4) * rowsP + N) * 16 + (t & 15)] = 0;
    }
  }
}

// ---------- binB: per-bucket slot assignment (LDS counters) + slot padding ----------
__global__ __launch_bounds__(1024) void binB_kernel(
    const int* __restrict__ gcount, const u32* __restrict__ bedge,
    int* __restrict__ deg, u16* __restrict__ colidx, int N) {
  __shared__ int cnt2[512];
  int b = blockIdx.x;
  int t = threadIdx.x;
  if (t < 512) cnt2[t] = 0;
  __syncthreads();
  int count = min(gcount[b], BCAP);
  const u32* lst = bedge + (size_t)b * BCAP;
  for (int i = t; i < count; i += 1024) {
    u32 v = lst[i];
    int local = v & 511;
    int slot = atomicAdd(&cnt2[local], 1);   // LDS atomic
    if (slot < SLOTS)
      colidx[((size_t)(b << 9) + local) * CSTR + slot] = (u16)(v >> 9);
  }
  __syncthreads();
  if (t < 512) {
    int node = (b << 9) + t;
    if (node < N) deg[node] = min(cnt2[t], SLOTS);
  }
  // pad slots [deg, CSTR) with dummy index N (zero row)
  for (int i = t; i < 512 * CSTR; i += 1024) {
    int local = i / CSTR;
    int slot = i - local * CSTR;
    int node = (b << 9) + local;
    if (node < N && slot >= min(cnt2[local], SLOTS))
      colidx[((size_t)(b << 9) + local) * CSTR + slot] = (u16)N;
  }
}

// ---------- panel aggregation: z = h + sum_{j->i} h[j] over one 32-col panel ----------
// panel = blockIdx&3 (3.2 MB, fits one XCD L2; round-robin dispatch puts panel p
// on XCDs {p,p+4} only -> kills the 8x h broadcast). Gather = 16 lanes x 4 B =
// exactly one 64 B line (fixes r11's sub-line transactions). colidx u16 (7.2 MB,
// L3-hot; fixes r11's colidx blowup). 4 nodes/wave, 8 gathers in flight.
__global__ __launch_bounds__(256) void aggregate_kernel(
    const u32* __restrict__ hp, const int* __restrict__ deg,
    const u16* __restrict__ colidx, u32* __restrict__ zp, int N, int rowsP) {
  int p = blockIdx.x & 3;
  int chunk = blockIdx.x >> 2;
  int wave = threadIdx.x >> 6;
  int lane = threadIdx.x & 63;
  int g = lane >> 4;      // node subgroup 0..3
  int c = lane & 15;      // u32 column within panel (2 bf16 cols)
  const u32* hpp = hp + (size_t)p * rowsP * 16;
  u32* zpp = zp + (size_t)p * rowsP * 16;
#pragma unroll 1
  for (int it = 0; it < 16; ++it) {
    int node = chunk * 256 + wave * 64 + it * 4 + g;
    bool live = node < N;
    int e = live ? deg[node] : 0;
    int em = max(e, __shfl_xor(e, 16, 64));
    em = max(em, __shfl_xor(em, 32, 64));
    int e8 = (em + 7) & ~7;
    const u16* nbr = colidx + (size_t)(live ? node : 0) * CSTR;
    u32 self = hpp[(size_t)(live ? node : N) * 16 + c];
    float a0 = bf2f((u16)(self & 0xffff));
    float a1 = bf2f((u16)(self >> 16));
    for (int k = 0; k < e8; k += 8) {
      int idx[8];
      u32 v[8];
#pragma unroll
      for (int i = 0; i < 8; ++i) idx[i] = nbr[k + i];
#pragma unroll
      for (int i = 0; i < 8; ++i) v[i] = hpp[(size_t)idx[i] * 16 + c];
#pragma unroll
      for (int i = 0; i < 8; ++i) {
        a0 += bf2f((u16)(v[i] & 0xffff));
        a1 += bf2f((u16)(v[i] >> 16));
      }
    }
    if (live) zpp[(size_t)node * 16 + c] = ((u32)f2bf(a1) << 16) | f2bf(a0);
  }
}

// ---------- GEMM: out = relu(A @ W + b) ----------
// W staged to LDS via regular L2-allocating vector loads (r12-proven).
// 256 rows/block x 512 thr, A-frags loaded before the barrier.
// STAGE 0: A panel-major (z) -> y row-major.
// STAGE 1: A row-major (y)   -> h panel-major.
// STAGE 2: A row-major (y)   -> fused relu(.)·Wh dot -> atomic gsum[batch[row]].
template <int STAGE>
__global__ __launch_bounds__(512) void gemm_kernel(
    const u16* __restrict__ A, const u16* __restrict__ Wth, const u16* __restrict__ Wtl,
    const float* __restrict__ bias, u16* __restrict__ outp,
    const float* __restrict__ Wh, const int* __restrict__ batch, float* __restrict__ gsum,
    int nrows, int rowsP) {
  __shared__ __attribute__((aligned(16))) u16 ldsWh[16384];
  __shared__ __attribute__((aligned(16))) u16 ldsWl[16384];
  int tid = threadIdx.x;
  {
    const uint4* gh = (const uint4*)Wth;
    const uint4* gl = (const uint4*)Wtl;
    uint4* lh = (uint4*)ldsWh;
    uint4* ll = (uint4*)ldsWl;
    uint4 th[4], tl[4];
#pragma unroll
    for (int i = 0; i < 4; ++i) { th[i] = gh[tid + i * 512]; tl[i] = gl[tid + i * 512]; }
#pragma unroll
    for (int i = 0; i < 4; ++i) { lh[tid + i * 512] = th[i]; ll[tid + i * 512] = tl[i]; }
  }
  int wave = tid >> 6, lane = tid & 63;
  int quad = lane >> 4, l16 = lane & 15;
  int rowbase = blockIdx.x * 256 + wave * 32;
  int mc0 = min(rowbase + l16, nrows - 1);
  int mc1 = min(rowbase + 16 + l16, nrows - 1);

  // preload all A-fragments; latency hides behind the staging drain at the barrier
  short8 a0[4], a1[4];
#pragma unroll
  for (int kt = 0; kt < 4; ++kt) {
    if (STAGE == 0) {
      // panel-major: frag cols kt*32+quad*8 live entirely in panel kt
      a0[kt] = *(const short8*)(A + ((size_t)kt * rowsP + mc0) * 32 + quad * 8);
      a1[kt] = *(const short8*)(A + ((size_t)kt * rowsP + mc1) * 32 + quad * 8);
    } else {
      a0[kt] = *(const short8*)(A + (size_t)mc0 * D + kt * 32 + quad * 8);
      a1[kt] = *(const short8*)(A + (size_t)mc1 * D + kt * 32 + quad * 8);
    }
  }

  __syncthreads();

  f32x4 acc[2][8];
  f32x4 zero = {0.f, 0.f, 0.f, 0.f};
#pragma unroll
  for (int mt = 0; mt < 2; ++mt)
#pragma unroll
    for (int nt = 0; nt < 8; ++nt) acc[mt][nt] = zero;

#pragma unroll
  for (int kt = 0; kt < 4; ++kt) {
#pragma unroll
    for (int nt = 0; nt < 8; ++nt) {
      int fo = ((kt * 8 + nt) * 64 + lane) * 8;
      short8 bh = *(const short8*)(ldsWh + fo);
      short8 bl = *(const short8*)(ldsWl + fo);
      acc[0][nt] = __builtin_amdgcn_mfma_f32_16x16x32_bf16(a0[kt], bh, acc[0][nt], 0, 0, 0);
      acc[0][nt] = __builtin_amdgcn_mfma_f32_16x16x32_bf16(a0[kt], bl, acc[0][nt], 0, 0, 0);
      acc[1][nt] = __builtin_amdgcn_mfma_f32_16x16x32_bf16(a1[kt], bh, acc[1][nt], 0, 0, 0);
      acc[1][nt] = __builtin_amdgcn_mfma_f32_16x16x32_bf16(a1[kt], bl, acc[1][nt], 0, 0, 0);
    }
  }

  if (STAGE == 2) {
    float dotr[2][4] = {{0.f, 0.f, 0.f, 0.f}, {0.f, 0.f, 0.f, 0.f}};
#pragma unroll
    for (int nt = 0; nt < 8; ++nt) {
      int col = nt * 16 + l16;
      float bv = bias[col];
      float wv = Wh[col];
#pragma unroll
      for (int mt = 0; mt < 2; ++mt)
#pragma unroll
        for (int r = 0; r < 4; ++r)
          dotr[mt][r] += fmaxf(acc[mt][nt][r] + bv, 0.f) * wv;
    }
#pragma unroll
    for (int m = 1; m < 16; m <<= 1) {
#pragma unroll
      for (int mt = 0; mt < 2; ++mt)
#pragma unroll
        for (int r = 0; r < 4; ++r) dotr[mt][r] += __shfl_xor(dotr[mt][r], m, 64);
    }
    if (l16 == 0) {
#pragma unroll
      for (int mt = 0; mt < 2; ++mt)
#pragma unroll
        for (int r = 0; r < 4; ++r) {
          int row = rowbase + mt * 16 + quad * 4 + r;
          if (row < nrows) atomicAdd(&gsum[batch[row]], dotr[mt][r]);
        }
    }
  } else {
#pragma unroll
    for (int nt = 0; nt < 8; ++nt) {
      int col = nt * 16 + l16;
      float bv = bias[col];
#pragma unroll
      for (int mt = 0; mt < 2; ++mt)
#pragma unroll
        for (int r = 0; r < 4; ++r) {
          int row = rowbase + mt * 16 + quad * 4 + r;
          if (row < nrows) {
            float v = fmaxf(acc[mt][nt][r] + bv, 0.f);
            if (STAGE == 0) {
              outp[(size_t)row * D + col] = f2bf(v);
            } else {
              // panel-major h: panel nt>>1, within-panel col (nt&1)*16+l16
              outp[((size_t)(nt >> 1) * rowsP + row) * 32 + (nt & 1) * 16 + l16] = f2bf(v);
            }
          }
        }
    }
  }
}

// ---------- finalize: per-graph mean via binary search on sorted batch ----------
__global__ void pool_final_kernel(const float* __restrict__ gsum, const int* __restrict__ batch,
                                  const float* __restrict__ bh, float* __restrict__ out,
                                  int G, int N) {
  int g = blockIdx.x * 256 + threadIdx.x;
  if (g >= G) return;
  int lo = 0, hi = N;
  while (lo < hi) { int mid = (lo + hi) >> 1; if (batch[mid] < g) lo = mid + 1; else hi = mid; }
  int lo2 = lo, hi2 = N;
  while (lo2 < hi2) { int mid = (lo2 + hi2) >> 1; if (batch[mid] < g + 1) lo2 = mid + 1; else hi2 = mid; }
  int c = lo2 - lo;
  out[g] = gsum[g] / fmaxf((float)c, 1.f) + bh[0];
}

extern "C" void kernel_launch(void* const* d_in, const int* in_sizes, int n_in,
                              void* d_out, int out_size, void* d_ws, size_t ws_size,
                              hipStream_t stream) {
  const float* x   = (const float*)d_in[0];
  const int* eidx  = (const int*)d_in[1];
  const int* batch = (const int*)d_in[2];
  const float* W1s = (const float*)d_in[3];
  const float* b1s = (const float*)d_in[4];
  const float* W2s = (const float*)d_in[5];
  const float* b2s = (const float*)d_in[6];
  const float* Wh  = (const float*)d_in[7];
  const float* bh  = (const float*)d_in[8];
  float* out = (float*)d_out;

  int N = in_sizes[0] / D;
  int E = in_sizes[1] / 2;
  int G = out_size;
  int L = in_sizes[3] / (D * D);
  int nbk = (N + 511) >> 9;           // 512-node dst-buckets (<=128)
  int wtotal = L * D * D;
  int nPairs = N * D / 2;
  int rowsP = N + 1;                  // panel rows incl. zero dummy row

  const int* src = eidx;
  const int* dst = eidx + E;

  char* p = (char*)d_ws;
  auto alloc = [&](size_t b) { char* r = p; p += (b + 255) & ~(size_t)255; return r; };
  u16*   hpnl   = (u16*)  alloc((size_t)4 * rowsP * 32 * 2);  // panel-major h
  u16*   xpnl   = (u16*)  alloc((size_t)4 * rowsP * 32 * 2);  // panel-major x(bf16)
  u16*   zpnl   = (u16*)  alloc((size_t)4 * rowsP * 32 * 2);  // panel-major z
  u16*   yb     = (u16*)  alloc((size_t)N * D * 2);           // row-major y
  size_t zbytes = (size_t)G * 4 + 512;                        // gsum + gcount
  char*  zblk   =         alloc(zbytes);
  float* gsum   = (float*)zblk;
  int*   gcount = (int*)(zblk + (size_t)G * 4);
  int*   deg    = (int*)  alloc((size_t)N * 4);
  u16*   colidx = (u16*)  alloc((size_t)N * CSTR * 2);
  u32*   bedge  = (u32*)  alloc((size_t)128 * BCAP * 4);
  u16*   W1th   = (u16*)  alloc((size_t)L * D * D * 2);
  u16*   W1tl   = (u16*)  alloc((size_t)L * D * D * 2);
  u16*   W2th   = (u16*)  alloc((size_t)L * D * D * 2);
  u16*   W2tl   = (u16*)  alloc((size_t)L * D * D * 2);

  hipMemsetAsync(zblk, 0, zbytes, stream);

  int nA = (E + 1023) / 1024;
  int nB = (wtotal + 1023) / 1024;
  int nC = (nPairs + 1023) / 1024;
  prep_kernel<<<nA + nB + nC + 1, 1024, 0, stream>>>(
      src, dst, x, W1s, W2s, gcount, bedge, W1th, W1tl, W2th, W2tl,
      (u32*)xpnl, (u32*)hpnl, E, nbk, wtotal, nPairs, nA, nB, nC, N, rowsP);
  binB_kernel<<<nbk, 1024, 0, stream>>>(gcount, bedge, deg, colidx, N);

  int agg_blocks = 4 * ((N + 255) / 256);
  int gemm_blocks = (N + 255) / 256;
  for (int l = 0; l < L; ++l) {
    const u16* hin = (l == 0) ? xpnl : hpnl;
    size_t wo = (size_t)l * D * D;
    aggregate_kernel<<<agg_blocks, 256, 0, stream>>>(
        (const u32*)hin, deg, colidx, (u32*)zpnl, N, rowsP);
    gemm_kernel<0><<<gemm_blocks, 512, 0, stream>>>(
        zpnl, W1th + wo, W1tl + wo, b1s + (size_t)l * D, yb,
        nullptr, nullptr, nullptr, N, rowsP);
    if (l < L - 1) {
      gemm_kernel<1><<<gemm_blocks, 512, 0, stream>>>(
          yb, W2th + wo, W2tl + wo, b2s + (size_t)l * D, hpnl,
          nullptr, nullptr, nullptr, N, rowsP);
    } else {
      gemm_kernel<2><<<gemm_blocks, 512, 0, stream>>>(
          yb, W2th + wo, W2tl + wo, b2s + (size_t)l * D, nullptr,
          Wh, batch, gsum, N, rowsP);
    }
  }
  pool_final_kernel<<<(G + 255) / 256, 256, 0, stream>>>(gsum, batch, bh, out, G, N);
}

// Round 14
// 444.453 us; speedup vs baseline: 1.1846x; 1.1846x over previous
//
#include <hip/hip_runtime.h>
#include <hip/hip_bf16.h>

#define D 128
#define SLOTS 64
#define CSTR 72     // colidx row stride; slots [deg,CSTR) hold dummy index N
#define BCAP 9216   // bucket capacity: mean 8192, +11 sigma

typedef short short8 __attribute__((ext_vector_type(8)));
typedef float f32x4 __attribute__((ext_vector_type(4)));
typedef unsigned short u16;
typedef unsigned int u32;

static __device__ __forceinline__ u16 f2bf(float f) {
  union { float f; unsigned u; } v; v.f = f;
  unsigned r = v.u + 0x7FFF + ((v.u >> 16) & 1);  // round-to-nearest-even
  return (u16)(r >> 16);
}
static __device__ __forceinline__ float bf2f(u16 h) {
  union { unsigned u; float f; } v; v.u = ((unsigned)h) << 16;
  return v.f;
}

// ---------- merged prep: binA | convertW | convertX | zero-row ----------
__global__ __launch_bounds__(1024) void prep_kernel(
    const int* __restrict__ src, const int* __restrict__ dst,
    const float* __restrict__ x, const float* __restrict__ W1,
    const float* __restrict__ W2, int* __restrict__ gcount,
    u32* __restrict__ bedge, u16* __restrict__ W1th, u16* __restrict__ W1tl,
    u16* __restrict__ W2th, u16* __restrict__ W2tl, u32* __restrict__ xb,
    u16* __restrict__ hb, int E, int nbk, int wtotal, int nPairs,
    int nA, int nB, int nC, int N) {
  __shared__ int cnt[128];
  __shared__ int base[128];
  int b = blockIdx.x, t = threadIdx.x;
  if (b < nA) {
    // binA: LDS-binned edge scatter into 512-node dst-buckets
    if (t < nbk) cnt[t] = 0;
    __syncthreads();
    int e = b * 1024 + t;
    int bk = 0, p = 0;
    u32 payload = 0;
    bool valid = e < E;
    if (valid) {
      int d = dst[e];
      bk = d >> 9;
      payload = ((u32)src[e] << 9) | (u32)(d & 511);
      p = atomicAdd(&cnt[bk], 1);      // LDS atomic
    }
    __syncthreads();
    if (t < nbk) base[t] = cnt[t] ? atomicAdd(&gcount[t], cnt[t]) : 0;
    __syncthreads();
    if (valid) {
      int pos = base[bk] + p;
      if (pos < BCAP) bedge[(size_t)bk * BCAP + pos] = payload;
    }
  } else if (b < nA + nB) {
    // convert weights: hi/lo split bf16 in MFMA-fragment-tiled order
    // ((kt*8+nt)*64+lane)*8+j  <-  W[k][n], k=kt*32+(lane>>4)*8+j, n=nt*16+(lane&15)
    int idx = (b - nA) * 1024 + t;
    if (idx < wtotal) {
      int l = idx >> 14;
      int r = idx & 16383;
      int j = r & 7;
      int lane = (r >> 3) & 63;
      int tt = r >> 9;
      int kt = tt >> 3, nt = tt & 7;
      int k = kt * 32 + (lane >> 4) * 8 + j;
      int n = nt * 16 + (lane & 15);
      size_t s = (size_t)l * D * D + (size_t)k * D + n;
      float w1 = W1[s], w2 = W2[s];
      u16 h1 = f2bf(w1), h2 = f2bf(w2);
      W1th[idx] = h1; W1tl[idx] = f2bf(w1 - bf2f(h1));
      W2th[idx] = h2; W2tl[idx] = f2bf(w2 - bf2f(h2));
    }
  } else if (b < nA + nB + nC) {
    // convert x -> bf16 packed pairs, 4 pairs/thread
    int i0 = (b - nA - nB) * 4096 + t * 4;
    if (i0 < nPairs) {
      float4 f0 = ((const float4*)x)[i0 >> 1];
      float4 f1 = ((const float4*)x)[(i0 >> 1) + 1];
      uint4 o;
      o.x = ((u32)f2bf(f0.y) << 16) | f2bf(f0.x);
      o.y = ((u32)f2bf(f0.w) << 16) | f2bf(f0.z);
      o.z = ((u32)f2bf(f1.y) << 16) | f2bf(f1.x);
      o.w = ((u32)f2bf(f1.w) << 16) | f2bf(f1.z);
      *(uint4*)(xb + i0) = o;
    }
  } else {
    // zero dummy row N of xb and hb
    if (t < 64) {
      ((u32*)xb)[(size_t)N * 64 + t] = 0;
      ((u32*)hb)[(size_t)N * 64 + t] = 0;
    }
  }
}

// ---------- binB: per-bucket slot assignment (LDS counters) + slot padding ----------
__global__ __launch_bounds__(1024) void binB_kernel(
    const int* __restrict__ gcount, const u32* __restrict__ bedge,
    int* __restrict__ deg, int* __restrict__ colidx, int N) {
  __shared__ int cnt2[512];
  int b = blockIdx.x;
  int t = threadIdx.x;
  if (t < 512) cnt2[t] = 0;
  __syncthreads();
  int count = min(gcount[b], BCAP);
  const u32* lst = bedge + (size_t)b * BCAP;
  for (int i = t; i < count; i += 1024) {
    u32 v = lst[i];
    int local = v & 511;
    int slot = atomicAdd(&cnt2[local], 1);   // LDS atomic
    if (slot < SLOTS)
      colidx[((size_t)(b << 9) + local) * CSTR + slot] = (int)(v >> 9);
  }
  __syncthreads();
  if (t < 512) {
    int node = (b << 9) + t;
    if (node < N) deg[node] = min(cnt2[t], SLOTS);
  }
  // pad slots [deg, CSTR) with dummy index N (zero row)
  for (int i = t; i < 512 * CSTR; i += 1024) {
    int local = i / CSTR;
    int slot = i - local * CSTR;
    int node = (b << 9) + local;
    if (node < N && slot >= min(cnt2[local], SLOTS))
      colidx[((size_t)(b << 9) + local) * CSTR + slot] = N;
  }
}

// ---------- aggregation: z = h + sum_{j->i} h[j]; 4 nodes/wave, uint4 gathers ----------
// lane = g*16+c: group g (node), c = 16B column chunk. One gather instruction
// moves 64 lanes x 16 B = 1 KB (full 256 B rows of 4 nodes) -- half the VMEM
// instruction count of the uint2 version (panel rounds proved instr-bound).
// Slot lists padded to CSTR with index N (zero row) -> branch-free 8-deep batches.
__global__ __launch_bounds__(256) void aggregate_kernel(
    const u16* __restrict__ hb, const int* __restrict__ deg,
    const int* __restrict__ colidx, u32* __restrict__ zb, int N) {
  int lane = threadIdx.x & 63;
  int wave = threadIdx.x >> 6;
  int g = lane >> 4, c = lane & 15;
  int node = blockIdx.x * 16 + wave * 4 + g;
  bool live = node < N;
  const uint4* hp = (const uint4*)hb;
  int e = live ? deg[node] : 0;
  int em = max(e, __shfl_xor(e, 16, 64));
  em = max(em, __shfl_xor(em, 32, 64));
  const int* nbr = colidx + (size_t)(live ? node : 0) * CSTR;
  uint4 s = hp[(size_t)(live ? node : N) * 16 + c];
  float a0 = bf2f((u16)(s.x & 0xffff)), a1 = bf2f((u16)(s.x >> 16));
  float a2 = bf2f((u16)(s.y & 0xffff)), a3 = bf2f((u16)(s.y >> 16));
  float a4 = bf2f((u16)(s.z & 0xffff)), a5 = bf2f((u16)(s.z >> 16));
  float a6 = bf2f((u16)(s.w & 0xffff)), a7 = bf2f((u16)(s.w >> 16));
  for (int k = 0; k < em; k += 8) {
    int idx[8];
    uint4 v[8];
#pragma unroll
    for (int i = 0; i < 8; ++i) idx[i] = nbr[k + i];   // broadcast within group
#pragma unroll
    for (int i = 0; i < 8; ++i) v[i] = hp[(size_t)idx[i] * 16 + c];
#pragma unroll
    for (int i = 0; i < 8; ++i) {
      a0 += bf2f((u16)(v[i].x & 0xffff)); a1 += bf2f((u16)(v[i].x >> 16));
      a2 += bf2f((u16)(v[i].y & 0xffff)); a3 += bf2f((u16)(v[i].y >> 16));
      a4 += bf2f((u16)(v[i].z & 0xffff)); a5 += bf2f((u16)(v[i].z >> 16));
      a6 += bf2f((u16)(v[i].w & 0xffff)); a7 += bf2f((u16)(v[i].w >> 16));
    }
  }
  if (live) {
    uint4 o;
    o.x = ((u32)f2bf(a1) << 16) | f2bf(a0);
    o.y = ((u32)f2bf(a3) << 16) | f2bf(a2);
    o.z = ((u32)f2bf(a5) << 16) | f2bf(a4);
    o.w = ((u32)f2bf(a7) << 16) | f2bf(a6);
    ((uint4*)zb)[(size_t)node * 16 + c] = o;
  }
}

// ---------- GEMM: out = relu(A @ W + b), A bf16 [nrows][128] ----------
// W staged to LDS via REGULAR vector loads (L2-allocating, r12-proven) -- all
// blocks share the same 64KB W, so L2 hits beat the global_load_lds DMA path.
// 256 rows/block x 512 thr, A-frags loaded before the barrier (r9-proven).
// Wave tiling: 2 m-tiles x 8 n-tiles, 2 MFMAs per product (a*wh + a*wl).
// LAST=0: write bf16. LAST=1: fused relu(.)·Wh dot -> atomic gsum[batch[row]].
template <int LAST>
__global__ __launch_bounds__(512) void gemm_kernel(
    const u16* __restrict__ A, const u16* __restrict__ Wth, const u16* __restrict__ Wtl,
    const float* __restrict__ bias, u16* __restrict__ outp,
    const float* __restrict__ Wh, const int* __restrict__ batch, float* __restrict__ gsum,
    int nrows) {
  __shared__ __attribute__((aligned(16))) u16 ldsWh[16384];
  __shared__ __attribute__((aligned(16))) u16 ldsWl[16384];
  int tid = threadIdx.x;
  {
    const uint4* gh = (const uint4*)Wth;
    const uint4* gl = (const uint4*)Wtl;
    uint4* lh = (uint4*)ldsWh;
    uint4* ll = (uint4*)ldsWl;
    uint4 th[4], tl[4];
#pragma unroll
    for (int i = 0; i < 4; ++i) { th[i] = gh[tid + i * 512]; tl[i] = gl[tid + i * 512]; }
#pragma unroll
    for (int i = 0; i < 4; ++i) { lh[tid + i * 512] = th[i]; ll[tid + i * 512] = tl[i]; }
  }
  int wave = tid >> 6, lane = tid & 63;
  int quad = lane >> 4, l16 = lane & 15;
  int rowbase = blockIdx.x * 256 + wave * 32;
  int mc0 = min(rowbase + l16, nrows - 1);
  int mc1 = min(rowbase + 16 + l16, nrows - 1);

  // preload all A-fragments; latency hides behind the staging drain at the barrier
  short8 a0[4], a1[4];
#pragma unroll
  for (int kt = 0; kt < 4; ++kt) {
    a0[kt] = *(const short8*)(A + (size_t)mc0 * D + kt * 32 + quad * 8);
    a1[kt] = *(const short8*)(A + (size_t)mc1 * D + kt * 32 + quad * 8);
  }

  __syncthreads();

  f32x4 acc[2][8];
  f32x4 zero = {0.f, 0.f, 0.f, 0.f};
#pragma unroll
  for (int mt = 0; mt < 2; ++mt)
#pragma unroll
    for (int nt = 0; nt < 8; ++nt) acc[mt][nt] = zero;

#pragma unroll
  for (int kt = 0; kt < 4; ++kt) {
#pragma unroll
    for (int nt = 0; nt < 8; ++nt) {
      int fo = ((kt * 8 + nt) * 64 + lane) * 8;
      short8 bh = *(const short8*)(ldsWh + fo);
      short8 bl = *(const short8*)(ldsWl + fo);
      acc[0][nt] = __builtin_amdgcn_mfma_f32_16x16x32_bf16(a0[kt], bh, acc[0][nt], 0, 0, 0);
      acc[0][nt] = __builtin_amdgcn_mfma_f32_16x16x32_bf16(a0[kt], bl, acc[0][nt], 0, 0, 0);
      acc[1][nt] = __builtin_amdgcn_mfma_f32_16x16x32_bf16(a1[kt], bh, acc[1][nt], 0, 0, 0);
      acc[1][nt] = __builtin_amdgcn_mfma_f32_16x16x32_bf16(a1[kt], bl, acc[1][nt], 0, 0, 0);
    }
  }

  if (LAST) {
    float dotr[2][4] = {{0.f, 0.f, 0.f, 0.f}, {0.f, 0.f, 0.f, 0.f}};
#pragma unroll
    for (int nt = 0; nt < 8; ++nt) {
      int col = nt * 16 + l16;
      float bv = bias[col];
      float wv = Wh[col];
#pragma unroll
      for (int mt = 0; mt < 2; ++mt)
#pragma unroll
        for (int r = 0; r < 4; ++r)
          dotr[mt][r] += fmaxf(acc[mt][nt][r] + bv, 0.f) * wv;
    }
#pragma unroll
    for (int m = 1; m < 16; m <<= 1) {
#pragma unroll
      for (int mt = 0; mt < 2; ++mt)
#pragma unroll
        for (int r = 0; r < 4; ++r) dotr[mt][r] += __shfl_xor(dotr[mt][r], m, 64);
    }
    if (l16 == 0) {
#pragma unroll
      for (int mt = 0; mt < 2; ++mt)
#pragma unroll
        for (int r = 0; r < 4; ++r) {
          int row = rowbase + mt * 16 + quad * 4 + r;
          if (row < nrows) atomicAdd(&gsum[batch[row]], dotr[mt][r]);
        }
    }
  } else {
#pragma unroll
    for (int nt = 0; nt < 8; ++nt) {
      int col = nt * 16 + l16;
      float bv = bias[col];
#pragma unroll
      for (int mt = 0; mt < 2; ++mt)
#pragma unroll
        for (int r = 0; r < 4; ++r) {
          int row = rowbase + mt * 16 + quad * 4 + r;
          if (row < nrows)
            outp[(size_t)row * D + col] = f2bf(fmaxf(acc[mt][nt][r] + bv, 0.f));
        }
    }
  }
}

// ---------- finalize: per-graph mean via binary search on sorted batch ----------
__global__ void pool_final_kernel(const float* __restrict__ gsum, const int* __restrict__ batch,
                                  const float* __restrict__ bh, float* __restrict__ out,
                                  int G, int N) {
  int g = blockIdx.x * 256 + threadIdx.x;
  if (g >= G) return;
  int lo = 0, hi = N;
  while (lo < hi) { int mid = (lo + hi) >> 1; if (batch[mid] < g) lo = mid + 1; else hi = mid; }
  int lo2 = lo, hi2 = N;
  while (lo2 < hi2) { int mid = (lo2 + hi2) >> 1; if (batch[mid] < g + 1) lo2 = mid + 1; else hi2 = mid; }
  int c = lo2 - lo;
  out[g] = gsum[g] / fmaxf((float)c, 1.f) + bh[0];
}

extern "C" void kernel_launch(void* const* d_in, const int* in_sizes, int n_in,
                              void* d_out, int out_size, void* d_ws, size_t ws_size,
                              hipStream_t stream) {
  const float* x   = (const float*)d_in[0];
  const int* eidx  = (const int*)d_in[1];
  const int* batch = (const int*)d_in[2];
  const float* W1s = (const float*)d_in[3];
  const float* b1s = (const float*)d_in[4];
  const float* W2s = (const float*)d_in[5];
  const float* b2s = (const float*)d_in[6];
  const float* Wh  = (const float*)d_in[7];
  const float* bh  = (const float*)d_in[8];
  float* out = (float*)d_out;

  int N = in_sizes[0] / D;
  int E = in_sizes[1] / 2;
  int G = out_size;
  int L = in_sizes[3] / (D * D);
  int nbk = (N + 511) >> 9;           // 512-node dst-buckets (<=128)
  int wtotal = L * D * D;
  int nPairs = N * D / 2;

  const int* src = eidx;
  const int* dst = eidx + E;

  char* p = (char*)d_ws;
  auto alloc = [&](size_t b) { char* r = p; p += (b + 255) & ~(size_t)255; return r; };
  u16*   hb     = (u16*)  alloc((size_t)(N + 1) * D * 2);   // +1 zero row
  u16*   xb     = (u16*)  alloc((size_t)(N + 1) * D * 2);   // +1 zero row
  u16*   zb     = (u16*)  alloc((size_t)N * D * 2);
  u16*   yb     = (u16*)  alloc((size_t)N * D * 2);
  size_t zbytes = (size_t)G * 4 + 512;                       // gsum + gcount
  char*  zblk   =         alloc(zbytes);
  float* gsum   = (float*)zblk;
  int*   gcount = (int*)(zblk + (size_t)G * 4);
  int*   deg    = (int*)  alloc((size_t)N * 4);
  int*   colidx = (int*)  alloc((size_t)N * CSTR * 4);
  u32*   bedge  = (u32*)  alloc((size_t)128 * BCAP * 4);
  u16*   W1th   = (u16*)  alloc((size_t)L * D * D * 2);
  u16*   W1tl   = (u16*)  alloc((size_t)L * D * D * 2);
  u16*   W2th   = (u16*)  alloc((size_t)L * D * D * 2);
  u16*   W2tl   = (u16*)  alloc((size_t)L * D * D * 2);

  hipMemsetAsync(zblk, 0, zbytes, stream);

  int nA = (E + 1023) / 1024;
  int nB = (wtotal + 1023) / 1024;
  int nC = (nPairs / 4 + 1023) / 1024;
  prep_kernel<<<nA + nB + nC + 1, 1024, 0, stream>>>(
      src, dst, x, W1s, W2s, gcount, bedge, W1th, W1tl, W2th, W2tl,
      (u32*)xb, hb, E, nbk, wtotal, nPairs, nA, nB, nC, N);
  binB_kernel<<<nbk, 1024, 0, stream>>>(gcount, bedge, deg, colidx, N);

  int gemm_blocks = (N + 255) / 256;
  for (int l = 0; l < L; ++l) {
    const u16* hin = (l == 0) ? xb : hb;
    aggregate_kernel<<<(N + 15) / 16, 256, 0, stream>>>(hin, deg, colidx, (u32*)zb, N);
    size_t wo = (size_t)l * D * D;
    gemm_kernel<0><<<gemm_blocks, 512, 0, stream>>>(
        zb, W1th + wo, W1tl + wo, b1s + (size_t)l * D, yb,
        nullptr, nullptr, nullptr, N);
    if (l < L - 1) {
      gemm_kernel<0><<<gemm_blocks, 512, 0, stream>>>(
          yb, W2th + wo, W2tl + wo, b2s + (size_t)l * D, hb,
          nullptr, nullptr, nullptr, N);
    } else {
      gemm_kernel<1><<<gemm_blocks, 512, 0, stream>>>(
          yb, W2th + wo, W2tl + wo, b2s + (size_t)l * D, nullptr,
          Wh, batch, gsum, N);
    }
  }
  pool_final_kernel<<<(G + 255) / 256, 256, 0, stream>>>(gsum, batch, bh, out, G, N);
}

// Round 15
// 418.466 us; speedup vs baseline: 1.2582x; 1.0621x over previous
//
#include <hip/hip_runtime.h>
#include <hip/hip_bf16.h>

#define D 128
#define SLOTS 64
#define CSTR 72     // colidx row stride (u16); slots [deg,CSTR) hold dummy index N
#define BCAP 9216   // bucket capacity: mean 8192, +11 sigma

typedef short short8 __attribute__((ext_vector_type(8)));
typedef float f32x4 __attribute__((ext_vector_type(4)));
typedef unsigned short u16;
typedef unsigned int u32;

static __device__ __forceinline__ u16 f2bf(float f) {
  union { float f; unsigned u; } v; v.f = f;
  unsigned r = v.u + 0x7FFF + ((v.u >> 16) & 1);  // round-to-nearest-even
  return (u16)(r >> 16);
}
static __device__ __forceinline__ float bf2f(u16 h) {
  union { unsigned u; float f; } v; v.u = ((unsigned)h) << 16;
  return v.f;
}

// ---------- merged prep: binA | convertW | convertX(2-panel) | zero-rows ----------
__global__ __launch_bounds__(1024) void prep_kernel(
    const int* __restrict__ src, const int* __restrict__ dst,
    const float* __restrict__ x, const float* __restrict__ W1,
    const float* __restrict__ W2, int* __restrict__ gcount,
    u32* __restrict__ bedge, u16* __restrict__ W1th, u16* __restrict__ W1tl,
    u16* __restrict__ W2th, u16* __restrict__ W2tl, u32* __restrict__ xp,
    u32* __restrict__ hp, int E, int nbk, int wtotal, int nPairs,
    int nA, int nB, int nC, int N, int rowsP) {
  __shared__ int cnt[128];
  __shared__ int base[128];
  int b = blockIdx.x, t = threadIdx.x;
  if (b < nA) {
    // binA: LDS-binned edge scatter into 512-node dst-buckets
    if (t < nbk) cnt[t] = 0;
    __syncthreads();
    int e = b * 1024 + t;
    int bk = 0, p = 0;
    u32 payload = 0;
    bool valid = e < E;
    if (valid) {
      int d = dst[e];
      bk = d >> 9;
      payload = ((u32)src[e] << 9) | (u32)(d & 511);
      p = atomicAdd(&cnt[bk], 1);      // LDS atomic
    }
    __syncthreads();
    if (t < nbk) base[t] = cnt[t] ? atomicAdd(&gcount[t], cnt[t]) : 0;
    __syncthreads();
    if (valid) {
      int pos = base[bk] + p;
      if (pos < BCAP) bedge[(size_t)bk * BCAP + pos] = payload;
    }
  } else if (b < nA + nB) {
    // convert weights: hi/lo split bf16 in MFMA-fragment-tiled order
    // ((kt*8+nt)*64+lane)*8+j  <-  W[k][n], k=kt*32+(lane>>4)*8+j, n=nt*16+(lane&15)
    int idx = (b - nA) * 1024 + t;
    if (idx < wtotal) {
      int l = idx >> 14;
      int r = idx & 16383;
      int j = r & 7;
      int lane = (r >> 3) & 63;
      int tt = r >> 9;
      int kt = tt >> 3, nt = tt & 7;
      int k = kt * 32 + (lane >> 4) * 8 + j;
      int n = nt * 16 + (lane & 15);
      size_t s = (size_t)l * D * D + (size_t)k * D + n;
      float w1 = W1[s], w2 = W2[s];
      u16 h1 = f2bf(w1), h2 = f2bf(w2);
      W1th[idx] = h1; W1tl[idx] = f2bf(w1 - bf2f(h1));
      W2th[idx] = h2; W2tl[idx] = f2bf(w2 - bf2f(h2));
    }
  } else if (b < nA + nB + nC) {
    // convert x -> bf16 packed pairs, 2-panel layout (panel = 64 cols = 32 u32)
    int i0 = (b - nA - nB) * 4096 + t * 4;
    if (i0 < nPairs) {
      int node = i0 >> 6, pr = i0 & 63;          // 4 consecutive pairs, same panel
      float4 f0 = ((const float4*)x)[i0 >> 1];
      float4 f1 = ((const float4*)x)[(i0 >> 1) + 1];
      uint4 o;
      o.x = ((u32)f2bf(f0.y) << 16) | f2bf(f0.x);
      o.y = ((u32)f2bf(f0.w) << 16) | f2bf(f0.z);
      o.z = ((u32)f2bf(f1.y) << 16) | f2bf(f1.x);
      o.w = ((u32)f2bf(f1.w) << 16) | f2bf(f1.z);
      *(uint4*)(xp + ((size_t)(pr >> 5) * rowsP + node) * 32 + (pr & 31)) = o;
    }
  } else {
    // zero dummy row N of both panels of xp and hp
    if (t < 64) {
      xp[((size_t)(t >> 5) * rowsP + N) * 32 + (t & 31)] = 0;
      hp[((size_t)(t >> 5) * rowsP + N) * 32 + (t & 31)] = 0;
    }
  }
}

// ---------- binB: per-bucket slot assignment (LDS counters) + slot padding ----------
__global__ __launch_bounds__(1024) void binB_kernel(
    const int* __restrict__ gcount, const u32* __restrict__ bedge,
    int* __restrict__ deg, u16* __restrict__ colidx, int N) {
  __shared__ int cnt2[512];
  int b = blockIdx.x;
  int t = threadIdx.x;
  if (t < 512) cnt2[t] = 0;
  __syncthreads();
  int count = min(gcount[b], BCAP);
  const u32* lst = bedge + (size_t)b * BCAP;
  for (int i = t; i < count; i += 1024) {
    u32 v = lst[i];
    int local = v & 511;
    int slot = atomicAdd(&cnt2[local], 1);   // LDS atomic
    if (slot < SLOTS)
      colidx[((size_t)(b << 9) + local) * CSTR + slot] = (u16)(v >> 9);
  }
  __syncthreads();
  if (t < 512) {
    int node = (b << 9) + t;
    if (node < N) deg[node] = min(cnt2[t], SLOTS);
  }
  // pad slots [deg, CSTR) with dummy index N (zero row)
  for (int i = t; i < 512 * CSTR; i += 1024) {
    int local = i / CSTR;
    int slot = i - local * CSTR;
    int node = (b << 9) + local;
    if (node < N && slot >= min(cnt2[local], SLOTS))
      colidx[((size_t)(b << 9) + local) * CSTR + slot] = (u16)N;
  }
}

// ---------- 2-panel aggregation: z = h + sum_{j->i} h[j] over one 64-col panel ----------
// panel = blockIdx&1 (6.4 MB); round-robin dispatch puts each panel on 4 XCDs only
// -> h broadcast 102 MB -> ~51 MB. Gather = 16 lanes x 8 B = 128 B half-row;
// 4 nodes/wave -> per-edge instruction count matches r12 (the flat axis per r14).
// colidx u16. Slot lists padded to CSTR with index N (zero row) -> branch-free.
__global__ __launch_bounds__(256) void aggregate_kernel(
    const u32* __restrict__ hp, const int* __restrict__ deg,
    const u16* __restrict__ colidx, u32* __restrict__ zp, int N, int rowsP) {
  int p = blockIdx.x & 1;
  int chunk = blockIdx.x >> 1;
  int lane = threadIdx.x & 63;
  int wave = threadIdx.x >> 6;
  int g = lane >> 4, c = lane & 15;   // group (node), uint2 chunk within panel
  int node = chunk * 16 + wave * 4 + g;
  bool live = node < N;
  const uint2* hpp = (const uint2*)(hp + (size_t)p * rowsP * 32);
  int e = live ? deg[node] : 0;
  int em = max(e, __shfl_xor(e, 16, 64));
  em = max(em, __shfl_xor(em, 32, 64));
  const u16* nbr = colidx + (size_t)(live ? node : 0) * CSTR;
  uint2 s = hpp[(size_t)(live ? node : N) * 16 + c];
  float a0 = bf2f((u16)(s.x & 0xffff)), a1 = bf2f((u16)(s.x >> 16));
  float a2 = bf2f((u16)(s.y & 0xffff)), a3 = bf2f((u16)(s.y >> 16));
  for (int k = 0; k < em; k += 8) {
    int idx[8];
    uint2 v[8];
#pragma unroll
    for (int i = 0; i < 8; ++i) idx[i] = nbr[k + i];   // broadcast within group
#pragma unroll
    for (int i = 0; i < 8; ++i) v[i] = hpp[(size_t)idx[i] * 16 + c];
#pragma unroll
    for (int i = 0; i < 8; ++i) {
      a0 += bf2f((u16)(v[i].x & 0xffff)); a1 += bf2f((u16)(v[i].x >> 16));
      a2 += bf2f((u16)(v[i].y & 0xffff)); a3 += bf2f((u16)(v[i].y >> 16));
    }
  }
  if (live) {
    uint2 o;
    o.x = ((u32)f2bf(a1) << 16) | f2bf(a0);
    o.y = ((u32)f2bf(a3) << 16) | f2bf(a2);
    ((uint2*)(zp + (size_t)p * rowsP * 32))[(size_t)node * 16 + c] = o;
  }
}

// ---------- GEMM: out = relu(A @ W + b) ----------
// W staged to LDS via regular L2-allocating vector loads (r12-proven).
// 256 rows/block x 512 thr, A-frags loaded before the barrier.
// STAGE 0: A 2-panel (z) -> y row-major.  STAGE 1: A row-major (y) -> h 2-panel.
// STAGE 2: A row-major (y) -> fused relu(.)·Wh dot -> atomic gsum[batch[row]].
template <int STAGE>
__global__ __launch_bounds__(512) void gemm_kernel(
    const u16* __restrict__ A, const u16* __restrict__ Wth, const u16* __restrict__ Wtl,
    const float* __restrict__ bias, u16* __restrict__ outp,
    const float* __restrict__ Wh, const int* __restrict__ batch, float* __restrict__ gsum,
    int nrows, int rowsP) {
  __shared__ __attribute__((aligned(16))) u16 ldsWh[16384];
  __shared__ __attribute__((aligned(16))) u16 ldsWl[16384];
  int tid = threadIdx.x;
  {
    const uint4* gh = (const uint4*)Wth;
    const uint4* gl = (const uint4*)Wtl;
    uint4* lh = (uint4*)ldsWh;
    uint4* ll = (uint4*)ldsWl;
    uint4 th[4], tl[4];
#pragma unroll
    for (int i = 0; i < 4; ++i) { th[i] = gh[tid + i * 512]; tl[i] = gl[tid + i * 512]; }
#pragma unroll
    for (int i = 0; i < 4; ++i) { lh[tid + i * 512] = th[i]; ll[tid + i * 512] = tl[i]; }
  }
  int wave = tid >> 6, lane = tid & 63;
  int quad = lane >> 4, l16 = lane & 15;
  int rowbase = blockIdx.x * 256 + wave * 32;
  int mc0 = min(rowbase + l16, nrows - 1);
  int mc1 = min(rowbase + 16 + l16, nrows - 1);

  // preload all A-fragments; latency hides behind the staging drain at the barrier
  short8 a0[4], a1[4];
#pragma unroll
  for (int kt = 0; kt < 4; ++kt) {
    if (STAGE == 0) {
      // 2-panel: cols kt*32+quad*8 live in panel kt>>1 at (kt&1)*32+quad*8
      const u16* base = A + ((size_t)(kt >> 1) * rowsP) * 64 + (kt & 1) * 32 + quad * 8;
      a0[kt] = *(const short8*)(base + (size_t)mc0 * 64);
      a1[kt] = *(const short8*)(base + (size_t)mc1 * 64);
    } else {
      a0[kt] = *(const short8*)(A + (size_t)mc0 * D + kt * 32 + quad * 8);
      a1[kt] = *(const short8*)(A + (size_t)mc1 * D + kt * 32 + quad * 8);
    }
  }

  __syncthreads();

  f32x4 acc[2][8];
  f32x4 zero = {0.f, 0.f, 0.f, 0.f};
#pragma unroll
  for (int mt = 0; mt < 2; ++mt)
#pragma unroll
    for (int nt = 0; nt < 8; ++nt) acc[mt][nt] = zero;

#pragma unroll
  for (int kt = 0; kt < 4; ++kt) {
#pragma unroll
    for (int nt = 0; nt < 8; ++nt) {
      int fo = ((kt * 8 + nt) * 64 + lane) * 8;
      short8 bh = *(const short8*)(ldsWh + fo);
      short8 bl = *(const short8*)(ldsWl + fo);
      acc[0][nt] = __builtin_amdgcn_mfma_f32_16x16x32_bf16(a0[kt], bh, acc[0][nt], 0, 0, 0);
      acc[0][nt] = __builtin_amdgcn_mfma_f32_16x16x32_bf16(a0[kt], bl, acc[0][nt], 0, 0, 0);
      acc[1][nt] = __builtin_amdgcn_mfma_f32_16x16x32_bf16(a1[kt], bh, acc[1][nt], 0, 0, 0);
      acc[1][nt] = __builtin_amdgcn_mfma_f32_16x16x32_bf16(a1[kt], bl, acc[1][nt], 0, 0, 0);
    }
  }

  if (STAGE == 2) {
    float dotr[2][4] = {{0.f, 0.f, 0.f, 0.f}, {0.f, 0.f, 0.f, 0.f}};
#pragma unroll
    for (int nt = 0; nt < 8; ++nt) {
      int col = nt * 16 + l16;
      float bv = bias[col];
      float wv = Wh[col];
#pragma unroll
      for (int mt = 0; mt < 2; ++mt)
#pragma unroll
        for (int r = 0; r < 4; ++r)
          dotr[mt][r] += fmaxf(acc[mt][nt][r] + bv, 0.f) * wv;
    }
#pragma unroll
    for (int m = 1; m < 16; m <<= 1) {
#pragma unroll
      for (int mt = 0; mt < 2; ++mt)
#pragma unroll
        for (int r = 0; r < 4; ++r) dotr[mt][r] += __shfl_xor(dotr[mt][r], m, 64);
    }
    if (l16 == 0) {
#pragma unroll
      for (int mt = 0; mt < 2; ++mt)
#pragma unroll
        for (int r = 0; r < 4; ++r) {
          int row = rowbase + mt * 16 + quad * 4 + r;
          if (row < nrows) atomicAdd(&gsum[batch[row]], dotr[mt][r]);
        }
    }
  } else {
#pragma unroll
    for (int nt = 0; nt < 8; ++nt) {
      int col = nt * 16 + l16;
      float bv = bias[col];
#pragma unroll
      for (int mt = 0; mt < 2; ++mt)
#pragma unroll
        for (int r = 0; r < 4; ++r) {
          int row = rowbase + mt * 16 + quad * 4 + r;
          if (row < nrows) {
            float v = fmaxf(acc[mt][nt][r] + bv, 0.f);
            if (STAGE == 0) {
              outp[(size_t)row * D + col] = f2bf(v);
            } else {
              // 2-panel h: panel nt>>2, within-panel col (nt&3)*16+l16
              outp[((size_t)(nt >> 2) * rowsP + row) * 64 + (nt & 3) * 16 + l16] = f2bf(v);
            }
          }
        }
    }
  }
}

// ---------- finalize: per-graph mean via binary search on sorted batch ----------
__global__ void pool_final_kernel(const float* __restrict__ gsum, const int* __restrict__ batch,
                                  const float* __restrict__ bh, float* __restrict__ out,
                                  int G, int N) {
  int g = blockIdx.x * 256 + threadIdx.x;
  if (g >= G) return;
  int lo = 0, hi = N;
  while (lo < hi) { int mid = (lo + hi) >> 1; if (batch[mid] < g) lo = mid + 1; else hi = mid; }
  int lo2 = lo, hi2 = N;
  while (lo2 < hi2) { int mid = (lo2 + hi2) >> 1; if (batch[mid] < g + 1) lo2 = mid + 1; else hi2 = mid; }
  int c = lo2 - lo;
  out[g] = gsum[g] / fmaxf((float)c, 1.f) + bh[0];
}

extern "C" void kernel_launch(void* const* d_in, const int* in_sizes, int n_in,
                              void* d_out, int out_size, void* d_ws, size_t ws_size,
                              hipStream_t stream) {
  const float* x   = (const float*)d_in[0];
  const int* eidx  = (const int*)d_in[1];
  const int* batch = (const int*)d_in[2];
  const float* W1s = (const float*)d_in[3];
  const float* b1s = (const float*)d_in[4];
  const float* W2s = (const float*)d_in[5];
  const float* b2s = (const float*)d_in[6];
  const float* Wh  = (const float*)d_in[7];
  const float* bh  = (const float*)d_in[8];
  float* out = (float*)d_out;

  int N = in_sizes[0] / D;
  int E = in_sizes[1] / 2;
  int G = out_size;
  int L = in_sizes[3] / (D * D);
  int nbk = (N + 511) >> 9;           // 512-node dst-buckets (<=128)
  int wtotal = L * D * D;
  int nPairs = N * D / 2;
  int rowsP = N + 1;                  // panel rows incl. zero dummy row

  const int* src = eidx;
  const int* dst = eidx + E;

  char* p = (char*)d_ws;
  auto alloc = [&](size_t b) { char* r = p; p += (b + 255) & ~(size_t)255; return r; };
  u16*   hpnl   = (u16*)  alloc((size_t)2 * rowsP * 64 * 2);  // 2-panel h
  u16*   xpnl   = (u16*)  alloc((size_t)2 * rowsP * 64 * 2);  // 2-panel x(bf16)
  u16*   zpnl   = (u16*)  alloc((size_t)2 * rowsP * 64 * 2);  // 2-panel z
  u16*   yb     = (u16*)  alloc((size_t)N * D * 2);           // row-major y
  size_t zbytes = (size_t)G * 4 + 512;                        // gsum + gcount
  char*  zblk   =         alloc(zbytes);
  float* gsum   = (float*)zblk;
  int*   gcount = (int*)(zblk + (size_t)G * 4);
  int*   deg    = (int*)  alloc((size_t)N * 4);
  u16*   colidx = (u16*)  alloc((size_t)N * CSTR * 2);
  u32*   bedge  = (u32*)  alloc((size_t)128 * BCAP * 4);
  u16*   W1th   = (u16*)  alloc((size_t)L * D * D * 2);
  u16*   W1tl   = (u16*)  alloc((size_t)L * D * D * 2);
  u16*   W2th   = (u16*)  alloc((size_t)L * D * D * 2);
  u16*   W2tl   = (u16*)  alloc((size_t)L * D * D * 2);

  hipMemsetAsync(zblk, 0, zbytes, stream);

  int nA = (E + 1023) / 1024;
  int nB = (wtotal + 1023) / 1024;
  int nC = (nPairs / 4 + 1023) / 1024;
  prep_kernel<<<nA + nB + nC + 1, 1024, 0, stream>>>(
      src, dst, x, W1s, W2s, gcount, bedge, W1th, W1tl, W2th, W2tl,
      (u32*)xpnl, (u32*)hpnl, E, nbk, wtotal, nPairs, nA, nB, nC, N, rowsP);
  binB_kernel<<<nbk, 1024, 0, stream>>>(gcount, bedge, deg, colidx, N);

  int agg_blocks = 2 * ((N + 15) / 16);
  int gemm_blocks = (N + 255) / 256;
  for (int l = 0; l < L; ++l) {
    const u16* hin = (l == 0) ? xpnl : hpnl;
    size_t wo = (size_t)l * D * D;
    aggregate_kernel<<<agg_blocks, 256, 0, stream>>>(
        (const u32*)hin, deg, colidx, (u32*)zpnl, N, rowsP);
    gemm_kernel<0><<<gemm_blocks, 512, 0, stream>>>(
        zpnl, W1th + wo, W1tl + wo, b1s + (size_t)l * D, yb,
        nullptr, nullptr, nullptr, N, rowsP);
    if (l < L - 1) {
      gemm_kernel<1><<<gemm_blocks, 512, 0, stream>>>(
          yb, W2th + wo, W2tl + wo, b2s + (size_t)l * D, hpnl,
          nullptr, nullptr, nullptr, N, rowsP);
    } else {
      gemm_kernel<2><<<gemm_blocks, 512, 0, stream>>>(
          yb, W2th + wo, W2tl + wo, b2s + (size_t)l * D, nullptr,
          Wh, batch, gsum, N, rowsP);
    }
  }
  pool_final_kernel<<<(G + 255) / 256, 256, 0, stream>>>(gsum, batch, bh, out, G, N);
}

// Round 16
// 398.729 us; speedup vs baseline: 1.3205x; 1.0495x over previous
//
#include <hip/hip_runtime.h>
#include <hip/hip_bf16.h>

#define D 128
#define SLOTS 64
#define CSTR 72     // colidx row stride (u16); slots [deg,CSTR) hold dummy index N
#define BCAP 9216   // bucket capacity: mean 8192, +11 sigma

typedef short short8 __attribute__((ext_vector_type(8)));
typedef float f32x4 __attribute__((ext_vector_type(4)));
typedef unsigned short u16;
typedef unsigned int u32;

static __device__ __forceinline__ u16 f2bf(float f) {
  union { float f; unsigned u; } v; v.f = f;
  unsigned r = v.u + 0x7FFF + ((v.u >> 16) & 1);  // round-to-nearest-even
  return (u16)(r >> 16);
}
static __device__ __forceinline__ float bf2f(u16 h) {
  union { unsigned u; float f; } v; v.u = ((unsigned)h) << 16;
  return v.f;
}

// ---------- merged prep: binA | convertW | convertX(2-panel) | zero-rows ----------
__global__ __launch_bounds__(1024) void prep_kernel(
    const int* __restrict__ src, const int* __restrict__ dst,
    const float* __restrict__ x, const float* __restrict__ W1,
    const float* __restrict__ W2, int* __restrict__ gcount,
    u32* __restrict__ bedge, u16* __restrict__ W1th, u16* __restrict__ W1tl,
    u16* __restrict__ W2th, u16* __restrict__ W2tl, u32* __restrict__ xp,
    u32* __restrict__ hp, int E, int nbk, int wtotal, int nPairs,
    int nA, int nB, int nC, int N, int rowsP) {
  __shared__ int cnt[128];
  __shared__ int base[128];
  int b = blockIdx.x, t = threadIdx.x;
  if (b < nA) {
    // binA: LDS-binned edge scatter into 512-node dst-buckets
    if (t < nbk) cnt[t] = 0;
    __syncthreads();
    int e = b * 1024 + t;
    int bk = 0, p = 0;
    u32 payload = 0;
    bool valid = e < E;
    if (valid) {
      int d = dst[e];
      bk = d >> 9;
      payload = ((u32)src[e] << 9) | (u32)(d & 511);
      p = atomicAdd(&cnt[bk], 1);      // LDS atomic
    }
    __syncthreads();
    if (t < nbk) base[t] = cnt[t] ? atomicAdd(&gcount[t], cnt[t]) : 0;
    __syncthreads();
    if (valid) {
      int pos = base[bk] + p;
      if (pos < BCAP) bedge[(size_t)bk * BCAP + pos] = payload;
    }
  } else if (b < nA + nB) {
    // convert weights: hi/lo split bf16 in MFMA-fragment-tiled order
    // ((kt*8+nt)*64+lane)*8+j  <-  W[k][n], k=kt*32+(lane>>4)*8+j, n=nt*16+(lane&15)
    int idx = (b - nA) * 1024 + t;
    if (idx < wtotal) {
      int l = idx >> 14;
      int r = idx & 16383;
      int j = r & 7;
      int lane = (r >> 3) & 63;
      int tt = r >> 9;
      int kt = tt >> 3, nt = tt & 7;
      int k = kt * 32 + (lane >> 4) * 8 + j;
      int n = nt * 16 + (lane & 15);
      size_t s = (size_t)l * D * D + (size_t)k * D + n;
      float w1 = W1[s], w2 = W2[s];
      u16 h1 = f2bf(w1), h2 = f2bf(w2);
      W1th[idx] = h1; W1tl[idx] = f2bf(w1 - bf2f(h1));
      W2th[idx] = h2; W2tl[idx] = f2bf(w2 - bf2f(h2));
    }
  } else if (b < nA + nB + nC) {
    // convert x -> bf16 packed pairs, 2-panel layout (panel = 64 cols = 32 u32)
    int i0 = (b - nA - nB) * 4096 + t * 4;
    if (i0 < nPairs) {
      int node = i0 >> 6, pr = i0 & 63;          // 4 consecutive pairs, same panel
      float4 f0 = ((const float4*)x)[i0 >> 1];
      float4 f1 = ((const float4*)x)[(i0 >> 1) + 1];
      uint4 o;
      o.x = ((u32)f2bf(f0.y) << 16) | f2bf(f0.x);
      o.y = ((u32)f2bf(f0.w) << 16) | f2bf(f0.z);
      o.z = ((u32)f2bf(f1.y) << 16) | f2bf(f1.x);
      o.w = ((u32)f2bf(f1.w) << 16) | f2bf(f1.z);
      *(uint4*)(xp + ((size_t)(pr >> 5) * rowsP + node) * 32 + (pr & 31)) = o;
    }
  } else {
    // zero dummy row N of both panels of xp and hp
    if (t < 64) {
      xp[((size_t)(t >> 5) * rowsP + N) * 32 + (t & 31)] = 0;
      hp[((size_t)(t >> 5) * rowsP + N) * 32 + (t & 31)] = 0;
    }
  }
}

// ---------- binB: per-bucket slot assignment (LDS counters) + slot padding ----------
__global__ __launch_bounds__(1024) void binB_kernel(
    const int* __restrict__ gcount, const u32* __restrict__ bedge,
    int* __restrict__ deg, u16* __restrict__ colidx, int N) {
  __shared__ int cnt2[512];
  int b = blockIdx.x;
  int t = threadIdx.x;
  if (t < 512) cnt2[t] = 0;
  __syncthreads();
  int count = min(gcount[b], BCAP);
  const u32* lst = bedge + (size_t)b * BCAP;
  for (int i = t; i < count; i += 1024) {
    u32 v = lst[i];
    int local = v & 511;
    int slot = atomicAdd(&cnt2[local], 1);   // LDS atomic
    if (slot < SLOTS)
      colidx[((size_t)(b << 9) + local) * CSTR + slot] = (u16)(v >> 9);
  }
  __syncthreads();
  if (t < 512) {
    int node = (b << 9) + t;
    if (node < N) deg[node] = min(cnt2[t], SLOTS);
  }
  // pad slots [deg, CSTR) with dummy index N (zero row)
  for (int i = t; i < 512 * CSTR; i += 1024) {
    int local = i / CSTR;
    int slot = i - local * CSTR;
    int node = (b << 9) + local;
    if (node < N && slot >= min(cnt2[local], SLOTS))
      colidx[((size_t)(b << 9) + local) * CSTR + slot] = (u16)N;
  }
}

// ---------- 2-panel aggregation: z = h + sum_{j->i} h[j] over one 64-col panel ----------
// panel = blockIdx&1 (6.4 MB); round-robin dispatch puts each panel on 4 XCDs only
// -> h broadcast 102 MB -> ~51 MB (r15-proven win). Gather = 16 lanes x 8 B.
__global__ __launch_bounds__(256) void aggregate_kernel(
    const u32* __restrict__ hp, const int* __restrict__ deg,
    const u16* __restrict__ colidx, u32* __restrict__ zp, int N, int rowsP) {
  int p = blockIdx.x & 1;
  int chunk = blockIdx.x >> 1;
  int lane = threadIdx.x & 63;
  int wave = threadIdx.x >> 6;
  int g = lane >> 4, c = lane & 15;   // group (node), uint2 chunk within panel
  int node = chunk * 16 + wave * 4 + g;
  bool live = node < N;
  const uint2* hpp = (const uint2*)(hp + (size_t)p * rowsP * 32);
  int e = live ? deg[node] : 0;
  int em = max(e, __shfl_xor(e, 16, 64));
  em = max(em, __shfl_xor(em, 32, 64));
  const u16* nbr = colidx + (size_t)(live ? node : 0) * CSTR;
  uint2 s = hpp[(size_t)(live ? node : N) * 16 + c];
  float a0 = bf2f((u16)(s.x & 0xffff)), a1 = bf2f((u16)(s.x >> 16));
  float a2 = bf2f((u16)(s.y & 0xffff)), a3 = bf2f((u16)(s.y >> 16));
  for (int k = 0; k < em; k += 8) {
    int idx[8];
    uint2 v[8];
#pragma unroll
    for (int i = 0; i < 8; ++i) idx[i] = nbr[k + i];   // broadcast within group
#pragma unroll
    for (int i = 0; i < 8; ++i) v[i] = hpp[(size_t)idx[i] * 16 + c];
#pragma unroll
    for (int i = 0; i < 8; ++i) {
      a0 += bf2f((u16)(v[i].x & 0xffff)); a1 += bf2f((u16)(v[i].x >> 16));
      a2 += bf2f((u16)(v[i].y & 0xffff)); a3 += bf2f((u16)(v[i].y >> 16));
    }
  }
  if (live) {
    uint2 o;
    o.x = ((u32)f2bf(a1) << 16) | f2bf(a0);
    o.y = ((u32)f2bf(a3) << 16) | f2bf(a2);
    ((uint2*)(zp + (size_t)p * rowsP * 32))[(size_t)node * 16 + c] = o;
  }
}

// ---------- GEMM: out = relu(A @ W + b) ----------
// 128 rows/block x 256 thr (4 waves x 32 rows), 64 KB LDS => 2 blocks/CU
// co-resident: one block's MFMA phase overlaps its CU-mate's W staging (196
// single-shot blocks had zero block-level pipelining). W staged via regular
// L2-allocating loads (r12). After MFMAs the W LDS is dead -> reused as a
// y[128][136] staging buffer so global stores are 8 coalesced uint4/thread
// instead of 64 scalar u16/thread.
// STAGE 0: A 2-panel (z) -> y row-major.  STAGE 1: A row-major (y) -> h 2-panel.
// STAGE 2: A row-major (y) -> fused relu(.)·Wh dot -> atomic gsum[batch[row]].
template <int STAGE>
__global__ __launch_bounds__(256) void gemm_kernel(
    const u16* __restrict__ A, const u16* __restrict__ Wth, const u16* __restrict__ Wtl,
    const float* __restrict__ bias, u16* __restrict__ outp,
    const float* __restrict__ Wh, const int* __restrict__ batch, float* __restrict__ gsum,
    int nrows, int rowsP) {
  __shared__ __attribute__((aligned(16))) u16 ldsW[32768];   // Wh|Wl, reused as y
  u16* ldsWh = ldsW;
  u16* ldsWl = ldsW + 16384;
  int tid = threadIdx.x;
  {
    const uint4* gh = (const uint4*)Wth;
    const uint4* gl = (const uint4*)Wtl;
    uint4 th[8], tl[8];
#pragma unroll
    for (int i = 0; i < 8; ++i) { th[i] = gh[tid + i * 256]; tl[i] = gl[tid + i * 256]; }
    uint4* lh = (uint4*)ldsWh;
    uint4* ll = (uint4*)ldsWl;
#pragma unroll
    for (int i = 0; i < 8; ++i) { lh[tid + i * 256] = th[i]; ll[tid + i * 256] = tl[i]; }
  }
  int wave = tid >> 6, lane = tid & 63;
  int quad = lane >> 4, l16 = lane & 15;
  int rowbase = blockIdx.x * 128 + wave * 32;
  int mc0 = min(rowbase + l16, nrows - 1);
  int mc1 = min(rowbase + 16 + l16, nrows - 1);

  // preload all A-fragments; latency hides behind the staging drain at the barrier
  short8 a0[4], a1[4];
#pragma unroll
  for (int kt = 0; kt < 4; ++kt) {
    if (STAGE == 0) {
      // 2-panel: cols kt*32+quad*8 live in panel kt>>1 at (kt&1)*32+quad*8
      const u16* base = A + ((size_t)(kt >> 1) * rowsP) * 64 + (kt & 1) * 32 + quad * 8;
      a0[kt] = *(const short8*)(base + (size_t)mc0 * 64);
      a1[kt] = *(const short8*)(base + (size_t)mc1 * 64);
    } else {
      a0[kt] = *(const short8*)(A + (size_t)mc0 * D + kt * 32 + quad * 8);
      a1[kt] = *(const short8*)(A + (size_t)mc1 * D + kt * 32 + quad * 8);
    }
  }

  __syncthreads();

  f32x4 acc[2][8];
  f32x4 zero = {0.f, 0.f, 0.f, 0.f};
#pragma unroll
  for (int mt = 0; mt < 2; ++mt)
#pragma unroll
    for (int nt = 0; nt < 8; ++nt) acc[mt][nt] = zero;

#pragma unroll
  for (int kt = 0; kt < 4; ++kt) {
#pragma unroll
    for (int nt = 0; nt < 8; ++nt) {
      int fo = ((kt * 8 + nt) * 64 + lane) * 8;
      short8 bh = *(const short8*)(ldsWh + fo);
      short8 bl = *(const short8*)(ldsWl + fo);
      acc[0][nt] = __builtin_amdgcn_mfma_f32_16x16x32_bf16(a0[kt], bh, acc[0][nt], 0, 0, 0);
      acc[0][nt] = __builtin_amdgcn_mfma_f32_16x16x32_bf16(a0[kt], bl, acc[0][nt], 0, 0, 0);
      acc[1][nt] = __builtin_amdgcn_mfma_f32_16x16x32_bf16(a1[kt], bh, acc[1][nt], 0, 0, 0);
      acc[1][nt] = __builtin_amdgcn_mfma_f32_16x16x32_bf16(a1[kt], bl, acc[1][nt], 0, 0, 0);
    }
  }

  if (STAGE == 2) {
    float dotr[2][4] = {{0.f, 0.f, 0.f, 0.f}, {0.f, 0.f, 0.f, 0.f}};
#pragma unroll
    for (int nt = 0; nt < 8; ++nt) {
      int col = nt * 16 + l16;
      float bv = bias[col];
      float wv = Wh[col];
#pragma unroll
      for (int mt = 0; mt < 2; ++mt)
#pragma unroll
        for (int r = 0; r < 4; ++r)
          dotr[mt][r] += fmaxf(acc[mt][nt][r] + bv, 0.f) * wv;
    }
#pragma unroll
    for (int m = 1; m < 16; m <<= 1) {
#pragma unroll
      for (int mt = 0; mt < 2; ++mt)
#pragma unroll
        for (int r = 0; r < 4; ++r) dotr[mt][r] += __shfl_xor(dotr[mt][r], m, 64);
    }
    if (l16 == 0) {
#pragma unroll
      for (int mt = 0; mt < 2; ++mt)
#pragma unroll
        for (int r = 0; r < 4; ++r) {
          int row = rowbase + mt * 16 + quad * 4 + r;
          if (row < nrows) atomicAdd(&gsum[batch[row]], dotr[mt][r]);
        }
    }
  } else {
    __syncthreads();   // all waves done reading W -> safe to overwrite ldsW as y
#pragma unroll
    for (int nt = 0; nt < 8; ++nt) {
      float bv = bias[nt * 16 + l16];
#pragma unroll
      for (int mt = 0; mt < 2; ++mt)
#pragma unroll
        for (int r = 0; r < 4; ++r) {
          int lrow = wave * 32 + mt * 16 + quad * 4 + r;
          ldsW[lrow * 136 + nt * 16 + l16] = f2bf(fmaxf(acc[mt][nt][r] + bv, 0.f));
        }
    }
    __syncthreads();
    // coalesced store: 128 rows x 128 cols in 16B chunks (2048 chunks, 8/thread)
#pragma unroll
    for (int i = 0; i < 8; ++i) {
      int chunk = i * 256 + tid;
      int r = chunk >> 4;
      int cc = (chunk & 15) * 8;
      int row = blockIdx.x * 128 + r;
      if (row < nrows) {
        uint4 v = *(const uint4*)(ldsW + r * 136 + cc);
        if (STAGE == 0) {
          *(uint4*)(outp + (size_t)row * D + cc) = v;
        } else {
          // 2-panel h: panel cc>>6, within-panel col cc&63
          *(uint4*)(outp + ((size_t)(cc >> 6) * rowsP + row) * 64 + (cc & 63)) = v;
        }
      }
    }
  }
}

// ---------- finalize: per-graph mean via binary search on sorted batch ----------
__global__ void pool_final_kernel(const float* __restrict__ gsum, const int* __restrict__ batch,
                                  const float* __restrict__ bh, float* __restrict__ out,
                                  int G, int N) {
  int g = blockIdx.x * 256 + threadIdx.x;
  if (g >= G) return;
  int lo = 0, hi = N;
  while (lo < hi) { int mid = (lo + hi) >> 1; if (batch[mid] < g) lo = mid + 1; else hi = mid; }
  int lo2 = lo, hi2 = N;
  while (lo2 < hi2) { int mid = (lo2 + hi2) >> 1; if (batch[mid] < g + 1) lo2 = mid + 1; else hi2 = mid; }
  int c = lo2 - lo;
  out[g] = gsum[g] / fmaxf((float)c, 1.f) + bh[0];
}

extern "C" void kernel_launch(void* const* d_in, const int* in_sizes, int n_in,
                              void* d_out, int out_size, void* d_ws, size_t ws_size,
                              hipStream_t stream) {
  const float* x   = (const float*)d_in[0];
  const int* eidx  = (const int*)d_in[1];
  const int* batch = (const int*)d_in[2];
  const float* W1s = (const float*)d_in[3];
  const float* b1s = (const float*)d_in[4];
  const float* W2s = (const float*)d_in[5];
  const float* b2s = (const float*)d_in[6];
  const float* Wh  = (const float*)d_in[7];
  const float* bh  = (const float*)d_in[8];
  float* out = (float*)d_out;

  int N = in_sizes[0] / D;
  int E = in_sizes[1] / 2;
  int G = out_size;
  int L = in_sizes[3] / (D * D);
  int nbk = (N + 511) >> 9;           // 512-node dst-buckets (<=128)
  int wtotal = L * D * D;
  int nPairs = N * D / 2;
  int rowsP = N + 1;                  // panel rows incl. zero dummy row

  const int* src = eidx;
  const int* dst = eidx + E;

  char* p = (char*)d_ws;
  auto alloc = [&](size_t b) { char* r = p; p += (b + 255) & ~(size_t)255; return r; };
  u16*   hpnl   = (u16*)  alloc((size_t)2 * rowsP * 64 * 2);  // 2-panel h
  u16*   xpnl   = (u16*)  alloc((size_t)2 * rowsP * 64 * 2);  // 2-panel x(bf16)
  u16*   zpnl   = (u16*)  alloc((size_t)2 * rowsP * 64 * 2);  // 2-panel z
  u16*   yb     = (u16*)  alloc((size_t)N * D * 2);           // row-major y
  size_t zbytes = (size_t)G * 4 + 512;                        // gsum + gcount
  char*  zblk   =         alloc(zbytes);
  float* gsum   = (float*)zblk;
  int*   gcount = (int*)(zblk + (size_t)G * 4);
  int*   deg    = (int*)  alloc((size_t)N * 4);
  u16*   colidx = (u16*)  alloc((size_t)N * CSTR * 2);
  u32*   bedge  = (u32*)  alloc((size_t)128 * BCAP * 4);
  u16*   W1th   = (u16*)  alloc((size_t)L * D * D * 2);
  u16*   W1tl   = (u16*)  alloc((size_t)L * D * D * 2);
  u16*   W2th   = (u16*)  alloc((size_t)L * D * D * 2);
  u16*   W2tl   = (u16*)  alloc((size_t)L * D * D * 2);

  hipMemsetAsync(zblk, 0, zbytes, stream);

  int nA = (E + 1023) / 1024;
  int nB = (wtotal + 1023) / 1024;
  int nC = (nPairs / 4 + 1023) / 1024;
  prep_kernel<<<nA + nB + nC + 1, 1024, 0, stream>>>(
      src, dst, x, W1s, W2s, gcount, bedge, W1th, W1tl, W2th, W2tl,
      (u32*)xpnl, (u32*)hpnl, E, nbk, wtotal, nPairs, nA, nB, nC, N, rowsP);
  binB_kernel<<<nbk, 1024, 0, stream>>>(gcount, bedge, deg, colidx, N);

  int agg_blocks = 2 * ((N + 15) / 16);
  int gemm_blocks = (N + 127) / 128;
  for (int l = 0; l < L; ++l) {
    const u16* hin = (l == 0) ? xpnl : hpnl;
    size_t wo = (size_t)l * D * D;
    aggregate_kernel<<<agg_blocks, 256, 0, stream>>>(
        (const u32*)hin, deg, colidx, (u32*)zpnl, N, rowsP);
    gemm_kernel<0><<<gemm_blocks, 256, 0, stream>>>(
        zpnl, W1th + wo, W1tl + wo, b1s + (size_t)l * D, yb,
        nullptr, nullptr, nullptr, N, rowsP);
    if (l < L - 1) {
      gemm_kernel<1><<<gemm_blocks, 256, 0, stream>>>(
          yb, W2th + wo, W2tl + wo, b2s + (size_t)l * D, hpnl,
          nullptr, nullptr, nullptr, N, rowsP);
    } else {
      gemm_kernel<2><<<gemm_blocks, 256, 0, stream>>>(
          yb, W2th + wo, W2tl + wo, b2s + (size_t)l * D, nullptr,
          Wh, batch, gsum, N, rowsP);
    }
  }
  pool_final_kernel<<<(G + 255) / 256, 256, 0, stream>>>(gsum, batch, bh, out, G, N);
}